// Round 2
// baseline (3962.601 us; speedup 1.0000x reference)
//
#include <hip/hip_runtime.h>

#define IN_F 256
#define HID  128
#define NCLS 40

// ---------------- zero ----------------
__global__ void zero4_kernel(float4* __restrict__ p, int n4) {
    int i = blockIdx.x * blockDim.x + threadIdx.x;
    if (i < n4) p[i] = make_float4(0.f, 0.f, 0.f, 0.f);
}

// ---------------- degrees ----------------
__global__ void degree_kernel(const int* __restrict__ src, const int* __restrict__ dst,
                              float* __restrict__ dout, float* __restrict__ din, int E) {
    int i = blockIdx.x * blockDim.x + threadIdx.x;
    if (i < E) {
        atomicAdd(&dout[src[i]], 1.0f);
        atomicAdd(&din[dst[i]], 1.0f);
    }
}

__global__ void rsqrt_kernel(float* __restrict__ d, int n) {
    int i = blockIdx.x * blockDim.x + threadIdx.x;
    if (i < n) d[i] = rsqrtf(fmaxf(d[i], 1.0f));
}

// ---------------- GEMM1: h1 = (x * rs_out[row]) @ W1   [N,256]@[256,128] ----------------
__global__ __launch_bounds__(256) void gemm1_kernel(
    const float* __restrict__ x, const float* __restrict__ W1,
    const float* __restrict__ rs_out, float* __restrict__ h1, int N) {
    __shared__ float ws[64][128];  // W chunk [k][c], 32 KB
    __shared__ float xs[64][64];   // x chunk [r][k], 16 KB
    const int tx  = threadIdx.x;
    const int c2  = tx & 63;   // this thread's col pair: 2*c2, 2*c2+1
    const int rg  = tx >> 6;   // row group 0..3 -> rows rg+4*i
    const int row0 = blockIdx.x * 64;

    float acc[16][2];
#pragma unroll
    for (int i = 0; i < 16; ++i) { acc[i][0] = 0.f; acc[i][1] = 0.f; }

    for (int k0 = 0; k0 < IN_F; k0 += 64) {
        // load W chunk: 64x128 = 8192 floats, 32 per thread, coalesced
#pragma unroll
        for (int j = 0; j < 32; ++j) {
            int idx = tx + 256 * j;
            int k = idx >> 7, c = idx & 127;
            ws[k][c] = W1[(k0 + k) * HID + c];
        }
        // load x chunk: 64 rows x 64 k, scaled by rs_out[row]
#pragma unroll
        for (int j = 0; j < 16; ++j) {
            int r = rg + 4 * j;
            int gr = row0 + r;
            float v = 0.f;
            if (gr < N) v = x[(long)gr * IN_F + k0 + c2] * rs_out[gr];
            xs[r][c2] = v;
        }
        __syncthreads();

        for (int k = 0; k < 64; k += 4) {
            float2 w0 = *(const float2*)&ws[k    ][2 * c2];
            float2 w1 = *(const float2*)&ws[k + 1][2 * c2];
            float2 w2 = *(const float2*)&ws[k + 2][2 * c2];
            float2 w3 = *(const float2*)&ws[k + 3][2 * c2];
#pragma unroll
            for (int i = 0; i < 16; ++i) {
                float4 xv = *(const float4*)&xs[rg + 4 * i][k];
                acc[i][0] = fmaf(xv.x, w0.x, acc[i][0]);
                acc[i][1] = fmaf(xv.x, w0.y, acc[i][1]);
                acc[i][0] = fmaf(xv.y, w1.x, acc[i][0]);
                acc[i][1] = fmaf(xv.y, w1.y, acc[i][1]);
                acc[i][0] = fmaf(xv.z, w2.x, acc[i][0]);
                acc[i][1] = fmaf(xv.z, w2.y, acc[i][1]);
                acc[i][0] = fmaf(xv.w, w3.x, acc[i][0]);
                acc[i][1] = fmaf(xv.w, w3.y, acc[i][1]);
            }
        }
        __syncthreads();
    }
#pragma unroll
    for (int i = 0; i < 16; ++i) {
        int gr = row0 + rg + 4 * i;
        if (gr < N) {
            float2 o; o.x = acc[i][0]; o.y = acc[i][1];
            *(float2*)&h1[(long)gr * HID + 2 * c2] = o;
        }
    }
}

// ---------------- scatter1: agg1[dst] += h1[src]  (128 feats, one wave/edge) ----------------
__global__ __launch_bounds__(256) void scatter1_kernel(
    const int* __restrict__ src, const int* __restrict__ dst,
    const float* __restrict__ h1, float* __restrict__ agg1, int E) {
    int gwid = (blockIdx.x * 256 + threadIdx.x) >> 6;  // wave id = edge id
    int lane = threadIdx.x & 63;
    if (gwid >= E) return;
    int s = src[gwid], d = dst[gwid];
    float2 v = *(const float2*)&h1[(long)s * HID + 2 * lane];
    float* a = &agg1[(long)d * HID + 2 * lane];
    atomicAdd(a,     v.x);
    atomicAdd(a + 1, v.y);
}

// ---------------- GEMM2: h2 = (relu(agg1*rs_in + b1) * rs_out) @ W2  [N,128]@[128,40] ----
__global__ __launch_bounds__(256) void gemm2_kernel(
    const float* __restrict__ agg1, const float* __restrict__ W2,
    const float* __restrict__ b1, const float* __restrict__ rs_in,
    const float* __restrict__ rs_out, float* __restrict__ h2, int N) {
    __shared__ float xs[64][128];       // layer-2 input tile, 32 KB
    __shared__ float ws[128][NCLS];     // 20 KB
    const int tx = threadIdx.x;
    const int row0 = blockIdx.x * 64;

    // load W2 (linear copy, same layout)
    for (int idx = tx; idx < 128 * NCLS; idx += 256)
        ((float*)ws)[idx] = W2[idx];
    // load + fuse: relu(agg1*rs_in + b1) * rs_out   (layer-2 pre-normalization!)
#pragma unroll
    for (int j = 0; j < 32; ++j) {
        int idx = tx + 256 * j;
        int r = idx >> 7, k = idx & 127;
        int gr = row0 + r;
        float v = 0.f;
        if (gr < N)
            v = fmaxf(fmaf(agg1[(long)gr * HID + k], rs_in[gr], b1[k]), 0.f) * rs_out[gr];
        xs[r][k] = v;
    }
    __syncthreads();

    const int wv = tx >> 6, lane = tx & 63;
    if (lane < NCLS) {
        for (int rb = 0; rb < 16; rb += 4) {
            int r = wv * 16 + rb;
            float a0 = 0.f, a1 = 0.f, a2 = 0.f, a3 = 0.f;
            for (int k = 0; k < 128; k += 4) {
                float w0 = ws[k][lane], w1 = ws[k + 1][lane];
                float w2 = ws[k + 2][lane], w3 = ws[k + 3][lane];
                float4 x0 = *(const float4*)&xs[r    ][k];
                float4 x1 = *(const float4*)&xs[r + 1][k];
                float4 x2 = *(const float4*)&xs[r + 2][k];
                float4 x3 = *(const float4*)&xs[r + 3][k];
                a0 = fmaf(x0.x, w0, fmaf(x0.y, w1, fmaf(x0.z, w2, fmaf(x0.w, w3, a0))));
                a1 = fmaf(x1.x, w0, fmaf(x1.y, w1, fmaf(x1.z, w2, fmaf(x1.w, w3, a1))));
                a2 = fmaf(x2.x, w0, fmaf(x2.y, w1, fmaf(x2.z, w2, fmaf(x2.w, w3, a2))));
                a3 = fmaf(x3.x, w0, fmaf(x3.y, w1, fmaf(x3.z, w2, fmaf(x3.w, w3, a3))));
            }
            int gr = row0 + r;
            if (gr     < N) h2[(long)gr * NCLS + lane] = a0;
            if (gr + 1 < N) h2[(long)(gr + 1) * NCLS + lane] = a1;
            if (gr + 2 < N) h2[(long)(gr + 2) * NCLS + lane] = a2;
            if (gr + 3 < N) h2[(long)(gr + 3) * NCLS + lane] = a3;
        }
    }
}

// ---------------- scatter2: out[dst] += h2[src]  (40 feats, one wave/edge) ----------------
__global__ __launch_bounds__(256) void scatter2_kernel(
    const int* __restrict__ src, const int* __restrict__ dst,
    const float* __restrict__ h2, float* __restrict__ out, int E) {
    int gwid = (blockIdx.x * 256 + threadIdx.x) >> 6;
    int lane = threadIdx.x & 63;
    if (gwid >= E) return;
    int s = src[gwid], d = dst[gwid];
    if (lane < NCLS)
        atomicAdd(&out[(long)d * NCLS + lane], h2[(long)s * NCLS + lane]);
}

// ---------------- final: out = out*rs_in[row] + b2[col] (in place) ----------------
__global__ void final_kernel(float* __restrict__ out, const float* __restrict__ rs_in,
                             const float* __restrict__ b2, int N) {
    int i = blockIdx.x * blockDim.x + threadIdx.x;
    int total = N * NCLS;
    if (i < total) {
        int r = i / NCLS;
        int c = i - r * NCLS;
        out[i] = fmaf(out[i], rs_in[r], b2[c]);
    }
}

extern "C" void kernel_launch(void* const* d_in, const int* in_sizes, int n_in,
                              void* d_out, int out_size, void* d_ws, size_t ws_size,
                              hipStream_t stream) {
    const float* x  = (const float*)d_in[0];
    const float* W1 = (const float*)d_in[1];
    const float* b1 = (const float*)d_in[2];
    const float* W2 = (const float*)d_in[3];
    const float* b2 = (const float*)d_in[4];
    const int*  src = (const int*)d_in[5];
    const int*  dst = (const int*)d_in[6];
    const int N = in_sizes[0] / IN_F;
    const int E = in_sizes[5];

    float* ws     = (float*)d_ws;
    float* rs_out = ws;                      // N
    float* rs_in  = ws + N;                  // N
    float* bufA   = ws + 2 * (long)N;        // N*128 : h1, later h2
    float* agg1   = bufA + (long)N * HID;    // N*128
    float* out    = (float*)d_out;

    // zero accumulators (fresh every call -> deterministic across graph replays)
    {
        int n4 = (2 * N) / 4;
        zero4_kernel<<<(n4 + 255) / 256, 256, 0, stream>>>((float4*)rs_out, n4);
        n4 = (N * HID) / 4;
        zero4_kernel<<<(n4 + 255) / 256, 256, 0, stream>>>((float4*)agg1, n4);
        n4 = (N * NCLS) / 4;
        zero4_kernel<<<(n4 + 255) / 256, 256, 0, stream>>>((float4*)out, n4);
    }

    degree_kernel<<<(E + 255) / 256, 256, 0, stream>>>(src, dst, rs_out, rs_in, E);
    rsqrt_kernel<<<(2 * N + 255) / 256, 256, 0, stream>>>(rs_out, 2 * N);

    gemm1_kernel<<<(N + 63) / 64, 256, 0, stream>>>(x, W1, rs_out, bufA, N);
    scatter1_kernel<<<(E + 3) / 4, 256, 0, stream>>>(src, dst, bufA, agg1, E);
    gemm2_kernel<<<(N + 63) / 64, 256, 0, stream>>>(agg1, W2, b1, rs_in, rs_out, bufA, N);
    scatter2_kernel<<<(E + 3) / 4, 256, 0, stream>>>(src, dst, bufA, out, E);
    final_kernel<<<(N * NCLS + 255) / 256, 256, 0, stream>>>(out, rs_in, b2, N);
}

// Round 3
// 1315.121 us; speedup vs baseline: 3.0131x; 3.0131x over previous
//
#include <hip/hip_runtime.h>

#define IN_F 256
#define HID  128
#define NCLS 40
#define SCAN_BS 1024

// ---------------- zero ----------------
__global__ void zero4_kernel(float4* __restrict__ p, int n4) {
    int i = blockIdx.x * blockDim.x + threadIdx.x;
    if (i < n4) p[i] = make_float4(0.f, 0.f, 0.f, 0.f);
}

// ---------------- degrees (int counts) ----------------
__global__ void degree_kernel(const int* __restrict__ src, const int* __restrict__ dst,
                              int* __restrict__ cnt_out, int* __restrict__ cnt_in, int E) {
    int i = blockIdx.x * blockDim.x + threadIdx.x;
    if (i < E) {
        atomicAdd(&cnt_out[src[i]], 1);
        atomicAdd(&cnt_in[dst[i]], 1);
    }
}

// counts -> rsqrt(max(c,1)) as float
__global__ void cvt_rsqrt_kernel(const int* __restrict__ cnt_out, const int* __restrict__ cnt_in,
                                 float* __restrict__ rs_out, float* __restrict__ rs_in, int N) {
    int i = blockIdx.x * blockDim.x + threadIdx.x;
    if (i < N) {
        rs_out[i] = rsqrtf((float)max(cnt_out[i], 1));
        rs_in[i]  = rsqrtf((float)max(cnt_in[i], 1));
    }
}

// ---------------- exclusive scan (3-phase) of cnt_in -> row_ptr ----------------
__global__ __launch_bounds__(SCAN_BS) void scan1_kernel(const int* __restrict__ deg,
                                                        int* __restrict__ out,
                                                        int* __restrict__ bsum, int n) {
    __shared__ int s[SCAN_BS];
    int tid = threadIdx.x;
    int i = blockIdx.x * SCAN_BS + tid;
    int v = (i < n) ? deg[i] : 0;
    s[tid] = v;
    __syncthreads();
    for (int off = 1; off < SCAN_BS; off <<= 1) {
        int t = (tid >= off) ? s[tid - off] : 0;
        __syncthreads();
        s[tid] += t;
        __syncthreads();
    }
    if (i < n) out[i] = s[tid] - v;  // exclusive within block
    if (tid == SCAN_BS - 1) bsum[blockIdx.x] = s[tid];
}

__global__ __launch_bounds__(256) void scan2_kernel(int* __restrict__ bsum, int nb) {
    __shared__ int s[256];
    int tid = threadIdx.x;
    int v = (tid < nb) ? bsum[tid] : 0;
    s[tid] = v;
    __syncthreads();
    for (int off = 1; off < 256; off <<= 1) {
        int t = (tid >= off) ? s[tid - off] : 0;
        __syncthreads();
        s[tid] += t;
        __syncthreads();
    }
    if (tid < nb) bsum[tid] = s[tid] - v;  // exclusive block offsets
}

__global__ void scan3_kernel(int* __restrict__ row_ptr, int* __restrict__ cursor,
                             const int* __restrict__ bsum, int n) {
    int i = blockIdx.x * blockDim.x + threadIdx.x;
    if (i < n) {
        int v = row_ptr[i] + bsum[i / SCAN_BS];
        row_ptr[i] = v;
        cursor[i]  = v;
    }
}

// ---------------- CSR fill: csr_src grouped by dst ----------------
__global__ void fill_kernel(const int* __restrict__ src, const int* __restrict__ dst,
                            int* __restrict__ cursor, int* __restrict__ csr_src, int E) {
    int i = blockIdx.x * blockDim.x + threadIdx.x;
    if (i < E) {
        int pos = atomicAdd(&cursor[dst[i]], 1);
        csr_src[pos] = src[i];
    }
}

// ---------------- GEMM1: h1 = (x * rs_out[row]) @ W1   [N,256]@[256,128] ----------------
__global__ __launch_bounds__(256) void gemm1_kernel(
    const float* __restrict__ x, const float* __restrict__ W1,
    const float* __restrict__ rs_out, float* __restrict__ h1, int N) {
    __shared__ float ws[64][128];
    __shared__ float xs[64][64];
    const int tx  = threadIdx.x;
    const int c2  = tx & 63;
    const int rg  = tx >> 6;
    const int row0 = blockIdx.x * 64;

    float acc[16][2];
#pragma unroll
    for (int i = 0; i < 16; ++i) { acc[i][0] = 0.f; acc[i][1] = 0.f; }

    for (int k0 = 0; k0 < IN_F; k0 += 64) {
#pragma unroll
        for (int j = 0; j < 32; ++j) {
            int idx = tx + 256 * j;
            int k = idx >> 7, c = idx & 127;
            ws[k][c] = W1[(k0 + k) * HID + c];
        }
#pragma unroll
        for (int j = 0; j < 16; ++j) {
            int r = rg + 4 * j;
            int gr = row0 + r;
            float v = 0.f;
            if (gr < N) v = x[(long)gr * IN_F + k0 + c2] * rs_out[gr];
            xs[r][c2] = v;
        }
        __syncthreads();

        for (int k = 0; k < 64; k += 4) {
            float2 w0 = *(const float2*)&ws[k    ][2 * c2];
            float2 w1 = *(const float2*)&ws[k + 1][2 * c2];
            float2 w2 = *(const float2*)&ws[k + 2][2 * c2];
            float2 w3 = *(const float2*)&ws[k + 3][2 * c2];
#pragma unroll
            for (int i = 0; i < 16; ++i) {
                float4 xv = *(const float4*)&xs[rg + 4 * i][k];
                acc[i][0] = fmaf(xv.x, w0.x, acc[i][0]);
                acc[i][1] = fmaf(xv.x, w0.y, acc[i][1]);
                acc[i][0] = fmaf(xv.y, w1.x, acc[i][0]);
                acc[i][1] = fmaf(xv.y, w1.y, acc[i][1]);
                acc[i][0] = fmaf(xv.z, w2.x, acc[i][0]);
                acc[i][1] = fmaf(xv.z, w2.y, acc[i][1]);
                acc[i][0] = fmaf(xv.w, w3.x, acc[i][0]);
                acc[i][1] = fmaf(xv.w, w3.y, acc[i][1]);
            }
        }
        __syncthreads();
    }
#pragma unroll
    for (int i = 0; i < 16; ++i) {
        int gr = row0 + rg + 4 * i;
        if (gr < N) {
            float2 o; o.x = acc[i][0]; o.y = acc[i][1];
            *(float2*)&h1[(long)gr * HID + 2 * c2] = o;
        }
    }
}

// ---------------- agg1 (pull): agg1[n] = sum_{e in CSR[n]} h1[src_e]  (128 f, wave/node) ----
__global__ __launch_bounds__(256) void agg1_kernel(
    const int* __restrict__ row_ptr, const int* __restrict__ row_end,
    const int* __restrict__ csr_src, const float* __restrict__ h1,
    float* __restrict__ agg, int N) {
    int node = (blockIdx.x * 256 + threadIdx.x) >> 6;
    int lane = threadIdx.x & 63;
    if (node >= N) return;
    int e = row_ptr[node], end = row_end[node];
    float ax = 0.f, ay = 0.f;
    for (; e + 4 <= end; e += 4) {
        int s0 = csr_src[e], s1 = csr_src[e + 1], s2 = csr_src[e + 2], s3 = csr_src[e + 3];
        float2 v0 = *(const float2*)&h1[(long)s0 * HID + 2 * lane];
        float2 v1 = *(const float2*)&h1[(long)s1 * HID + 2 * lane];
        float2 v2 = *(const float2*)&h1[(long)s2 * HID + 2 * lane];
        float2 v3 = *(const float2*)&h1[(long)s3 * HID + 2 * lane];
        ax += (v0.x + v1.x) + (v2.x + v3.x);
        ay += (v0.y + v1.y) + (v2.y + v3.y);
    }
    for (; e < end; ++e) {
        int s = csr_src[e];
        float2 v = *(const float2*)&h1[(long)s * HID + 2 * lane];
        ax += v.x; ay += v.y;
    }
    float2 o; o.x = ax; o.y = ay;
    *(float2*)&agg[(long)node * HID + 2 * lane] = o;
}

// ---------------- GEMM2: h2 = (relu(agg1*rs_in + b1) * rs_out) @ W2  [N,128]@[128,40] ----
__global__ __launch_bounds__(256) void gemm2_kernel(
    const float* __restrict__ agg1, const float* __restrict__ W2,
    const float* __restrict__ b1, const float* __restrict__ rs_in,
    const float* __restrict__ rs_out, float* __restrict__ h2, int N) {
    __shared__ float xs[64][128];
    __shared__ float ws[128][NCLS];
    const int tx = threadIdx.x;
    const int row0 = blockIdx.x * 64;

    for (int idx = tx; idx < 128 * NCLS; idx += 256)
        ((float*)ws)[idx] = W2[idx];
#pragma unroll
    for (int j = 0; j < 32; ++j) {
        int idx = tx + 256 * j;
        int r = idx >> 7, k = idx & 127;
        int gr = row0 + r;
        float v = 0.f;
        if (gr < N)
            v = fmaxf(fmaf(agg1[(long)gr * HID + k], rs_in[gr], b1[k]), 0.f) * rs_out[gr];
        xs[r][k] = v;
    }
    __syncthreads();

    const int wv = tx >> 6, lane = tx & 63;
    if (lane < NCLS) {
        for (int rb = 0; rb < 16; rb += 4) {
            int r = wv * 16 + rb;
            float a0 = 0.f, a1 = 0.f, a2 = 0.f, a3 = 0.f;
            for (int k = 0; k < 128; k += 4) {
                float w0 = ws[k][lane], w1 = ws[k + 1][lane];
                float w2 = ws[k + 2][lane], w3 = ws[k + 3][lane];
                float4 x0 = *(const float4*)&xs[r    ][k];
                float4 x1 = *(const float4*)&xs[r + 1][k];
                float4 x2 = *(const float4*)&xs[r + 2][k];
                float4 x3 = *(const float4*)&xs[r + 3][k];
                a0 = fmaf(x0.x, w0, fmaf(x0.y, w1, fmaf(x0.z, w2, fmaf(x0.w, w3, a0))));
                a1 = fmaf(x1.x, w0, fmaf(x1.y, w1, fmaf(x1.z, w2, fmaf(x1.w, w3, a1))));
                a2 = fmaf(x2.x, w0, fmaf(x2.y, w1, fmaf(x2.z, w2, fmaf(x2.w, w3, a2))));
                a3 = fmaf(x3.x, w0, fmaf(x3.y, w1, fmaf(x3.z, w2, fmaf(x3.w, w3, a3))));
            }
            int gr = row0 + r;
            if (gr     < N) h2[(long)gr * NCLS + lane] = a0;
            if (gr + 1 < N) h2[(long)(gr + 1) * NCLS + lane] = a1;
            if (gr + 2 < N) h2[(long)(gr + 2) * NCLS + lane] = a2;
            if (gr + 3 < N) h2[(long)(gr + 3) * NCLS + lane] = a3;
        }
    }
}

// ---------------- agg2 (pull) + epilogue: out[n] = (sum h2[src]) * rs_in[n] + b2 ----------
__global__ __launch_bounds__(256) void agg2_kernel(
    const int* __restrict__ row_ptr, const int* __restrict__ row_end,
    const int* __restrict__ csr_src, const float* __restrict__ h2,
    const float* __restrict__ rs_in, const float* __restrict__ b2,
    float* __restrict__ out, int N) {
    int node = (blockIdx.x * 256 + threadIdx.x) >> 6;
    int lane = threadIdx.x & 63;
    if (node >= N || lane >= NCLS) return;
    int e = row_ptr[node], end = row_end[node];
    float a = 0.f;
    for (; e + 4 <= end; e += 4) {
        int s0 = csr_src[e], s1 = csr_src[e + 1], s2 = csr_src[e + 2], s3 = csr_src[e + 3];
        float v0 = h2[(long)s0 * NCLS + lane];
        float v1 = h2[(long)s1 * NCLS + lane];
        float v2 = h2[(long)s2 * NCLS + lane];
        float v3 = h2[(long)s3 * NCLS + lane];
        a += (v0 + v1) + (v2 + v3);
    }
    for (; e < end; ++e)
        a += h2[(long)csr_src[e] * NCLS + lane];
    out[(long)node * NCLS + lane] = fmaf(a, rs_in[node], b2[lane]);
}

extern "C" void kernel_launch(void* const* d_in, const int* in_sizes, int n_in,
                              void* d_out, int out_size, void* d_ws, size_t ws_size,
                              hipStream_t stream) {
    const float* x  = (const float*)d_in[0];
    const float* W1 = (const float*)d_in[1];
    const float* b1 = (const float*)d_in[2];
    const float* W2 = (const float*)d_in[3];
    const float* b2 = (const float*)d_in[4];
    const int*  src = (const int*)d_in[5];
    const int*  dst = (const int*)d_in[6];
    const int N = in_sizes[0] / IN_F;
    const int E = in_sizes[5];
    const int NB = (N + SCAN_BS - 1) / SCAN_BS;  // scan blocks (98 for N=100K)

    float* wsf    = (float*)d_ws;
    float* rs_out = wsf;                          // N f
    float* rs_in  = wsf + N;                      // N f
    int*   cnt_out= (int*)(wsf + 2 * (long)N);    // N i
    int*   cnt_in = cnt_out + N;                  // N i
    int*   row_ptr= cnt_in + N;                   // N i
    int*   cursor = row_ptr + N;                  // N i
    int*   bsum   = cursor + N;                   // 256 i
    int*   csr_src= bsum + 256;                   // E i
    float* bufA   = (float*)(csr_src + E);        // N*128 f : h1, then h2
    float* agg1   = bufA + (long)N * HID;         // N*128 f

    // zero the degree counters (fresh every call)
    {
        int n4 = (2 * N) / 4;
        zero4_kernel<<<(n4 + 255) / 256, 256, 0, stream>>>((float4*)cnt_out, n4);
    }

    degree_kernel<<<(E + 255) / 256, 256, 0, stream>>>(src, dst, cnt_out, cnt_in, E);
    cvt_rsqrt_kernel<<<(N + 255) / 256, 256, 0, stream>>>(cnt_out, cnt_in, rs_out, rs_in, N);

    // CSR build (grouped by dst)
    scan1_kernel<<<NB, SCAN_BS, 0, stream>>>(cnt_in, row_ptr, bsum, N);
    scan2_kernel<<<1, 256, 0, stream>>>(bsum, NB);
    scan3_kernel<<<(N + 255) / 256, 256, 0, stream>>>(row_ptr, cursor, bsum, N);
    fill_kernel<<<(E + 255) / 256, 256, 0, stream>>>(src, dst, cursor, csr_src, E);
    // after fill, cursor[i] == row end

    gemm1_kernel<<<(N + 63) / 64, 256, 0, stream>>>(x, W1, rs_out, bufA, N);
    agg1_kernel<<<(N * 64 + 255) / 256, 256, 0, stream>>>(row_ptr, cursor, csr_src, bufA, agg1, N);
    gemm2_kernel<<<(N + 63) / 64, 256, 0, stream>>>(agg1, W2, b1, rs_in, rs_out, bufA, N);
    agg2_kernel<<<(N * 64 + 255) / 256, 256, 0, stream>>>(row_ptr, cursor, csr_src, bufA,
                                                          rs_in, b2, (float*)d_out, N);
}

// Round 4
// 974.041 us; speedup vs baseline: 4.0682x; 1.3502x over previous
//
#include <hip/hip_runtime.h>

#define IN_F 256
#define HID  128
#define NCLS 40
#define SCAN_BS 1024

typedef __attribute__((ext_vector_type(8))) short bf16x8;
typedef __attribute__((ext_vector_type(4))) float f32x4;

static __device__ __forceinline__ unsigned short f2bf(float f) {
    unsigned u = __builtin_bit_cast(unsigned, f);
    u += 0x7fffu + ((u >> 16) & 1u);   // round-to-nearest-even
    return (unsigned short)(u >> 16);
}

// ---------------- zero ----------------
__global__ void zero4_kernel(float4* __restrict__ p, int n4) {
    int i = blockIdx.x * blockDim.x + threadIdx.x;
    if (i < n4) p[i] = make_float4(0.f, 0.f, 0.f, 0.f);
}

// ---------------- degrees (int counts) ----------------
__global__ void degree_kernel(const int* __restrict__ src, const int* __restrict__ dst,
                              int* __restrict__ cnt_out, int* __restrict__ cnt_in, int E) {
    int i = blockIdx.x * blockDim.x + threadIdx.x;
    if (i < E) {
        atomicAdd(&cnt_out[src[i]], 1);
        atomicAdd(&cnt_in[dst[i]], 1);
    }
}

__global__ void cvt_rsqrt_kernel(const int* __restrict__ cnt_out, const int* __restrict__ cnt_in,
                                 float* __restrict__ rs_out, float* __restrict__ rs_in, int N) {
    int i = blockIdx.x * blockDim.x + threadIdx.x;
    if (i < N) {
        rs_out[i] = rsqrtf((float)max(cnt_out[i], 1));
        rs_in[i]  = rsqrtf((float)max(cnt_in[i], 1));
    }
}

// ---------------- exclusive scan (3-phase) of cnt_in -> row_ptr ----------------
__global__ __launch_bounds__(SCAN_BS) void scan1_kernel(const int* __restrict__ deg,
                                                        int* __restrict__ out,
                                                        int* __restrict__ bsum, int n) {
    __shared__ int s[SCAN_BS];
    int tid = threadIdx.x;
    int i = blockIdx.x * SCAN_BS + tid;
    int v = (i < n) ? deg[i] : 0;
    s[tid] = v;
    __syncthreads();
    for (int off = 1; off < SCAN_BS; off <<= 1) {
        int t = (tid >= off) ? s[tid - off] : 0;
        __syncthreads();
        s[tid] += t;
        __syncthreads();
    }
    if (i < n) out[i] = s[tid] - v;
    if (tid == SCAN_BS - 1) bsum[blockIdx.x] = s[tid];
}

__global__ __launch_bounds__(256) void scan2_kernel(int* __restrict__ bsum, int nb) {
    __shared__ int s[256];
    int tid = threadIdx.x;
    int v = (tid < nb) ? bsum[tid] : 0;
    s[tid] = v;
    __syncthreads();
    for (int off = 1; off < 256; off <<= 1) {
        int t = (tid >= off) ? s[tid - off] : 0;
        __syncthreads();
        s[tid] += t;
        __syncthreads();
    }
    if (tid < nb) bsum[tid] = s[tid] - v;
}

__global__ void scan3_kernel(int* __restrict__ row_ptr, int* __restrict__ cursor,
                             const int* __restrict__ bsum, int n) {
    int i = blockIdx.x * blockDim.x + threadIdx.x;
    if (i < n) {
        int v = row_ptr[i] + bsum[i / SCAN_BS];
        row_ptr[i] = v;
        cursor[i]  = v;
    }
}

// ---------------- CSR fill ----------------
__global__ void fill_kernel(const int* __restrict__ src, const int* __restrict__ dst,
                            int* __restrict__ cursor, int* __restrict__ csr_src, int E) {
    int i = blockIdx.x * blockDim.x + threadIdx.x;
    if (i < E) {
        int pos = atomicAdd(&cursor[dst[i]], 1);
        csr_src[pos] = src[i];
    }
}

// ---------------- GEMM1 (MFMA bf16): h1b = bf16((x*rs_out) @ W1)  [N,256]@[256,128] ------
// Block: 256 thr = 4 waves; wave computes 16 rows x 128 cols, K=256.
// W1 (bf16) fully resident in LDS, col-major [col][k], XOR-swizzled 16B slots.
__global__ __launch_bounds__(256) void gemm1_kernel(
    const float* __restrict__ x, const float* __restrict__ W1,
    const float* __restrict__ rs_out, unsigned short* __restrict__ h1b, int N) {
    __shared__ unsigned short Wl[32768];  // 64 KB

    const int tx = threadIdx.x;
    // stage W1 -> bf16 LDS (coalesced float4 global reads)
#pragma unroll
    for (int e = 0; e < 32; ++e) {
        int base = (tx + 256 * e) * 4;          // element index in [k][col] row-major
        float4 w = *(const float4*)&W1[base];
        int k = base >> 7;
        int c0 = base & 127;
        float wv[4] = {w.x, w.y, w.z, w.w};
#pragma unroll
        for (int q = 0; q < 4; ++q) {
            int col = c0 + q;
            int byte = col * 512 + k * 2;
            byte ^= (col & 7) << 4;             // swizzle: conflict-free b128 reads
            Wl[byte >> 1] = f2bf(wv[q]);
        }
    }
    __syncthreads();

    const int wv_ = tx >> 6, lane = tx & 63;
    const int r0 = blockIdx.x * 64 + wv_ * 16;
    const int arow = r0 + (lane & 15);
    const int arow_c = min(arow, N - 1);
    const float rs = rs_out[arow_c];
    const long xbase = (long)arow_c * IN_F + (lane >> 4) * 8;

    // load all A fragments (8 k-steps x 8 f32), scale, convert to bf16
    bf16x8 a8[8];
#pragma unroll
    for (int ks = 0; ks < 8; ++ks) {
        float4 p0 = *(const float4*)&x[xbase + ks * 32];
        float4 p1 = *(const float4*)&x[xbase + ks * 32 + 4];
        bf16x8 a;
        a[0] = (short)f2bf(p0.x * rs); a[1] = (short)f2bf(p0.y * rs);
        a[2] = (short)f2bf(p0.z * rs); a[3] = (short)f2bf(p0.w * rs);
        a[4] = (short)f2bf(p1.x * rs); a[5] = (short)f2bf(p1.y * rs);
        a[6] = (short)f2bf(p1.z * rs); a[7] = (short)f2bf(p1.w * rs);
        a8[ks] = a;
    }

    f32x4 acc[8];
#pragma unroll
    for (int nf = 0; nf < 8; ++nf) acc[nf] = (f32x4){0.f, 0.f, 0.f, 0.f};

#pragma unroll
    for (int ks = 0; ks < 8; ++ks) {
#pragma unroll
        for (int nf = 0; nf < 8; ++nf) {
            int col = nf * 16 + (lane & 15);
            int kb  = ks * 32 + (lane >> 4) * 8;
            int byte = col * 512 + kb * 2;
            byte ^= (col & 7) << 4;
            bf16x8 b = *(const bf16x8*)((const char*)Wl + byte);
            acc[nf] = __builtin_amdgcn_mfma_f32_16x16x32_bf16(a8[ks], b, acc[nf], 0, 0, 0);
        }
    }

    // epilogue: C/D layout col=lane&15, row=(lane>>4)*4+j  -> bf16 store
#pragma unroll
    for (int nf = 0; nf < 8; ++nf) {
#pragma unroll
        for (int j = 0; j < 4; ++j) {
            int row = r0 + (lane >> 4) * 4 + j;
            if (row < N)
                h1b[(long)row * HID + nf * 16 + (lane & 15)] = f2bf(acc[nf][j]);
        }
    }
}

// ---------------- agg1 (pull): agg[n] = sum h1b[src]  (bf16 gather, f32 accum) ----------
__global__ __launch_bounds__(256) void agg1_kernel(
    const int* __restrict__ row_ptr, const int* __restrict__ row_end,
    const int* __restrict__ csr_src, const unsigned* __restrict__ h1b2,  // [N][64] uint
    float* __restrict__ agg, int N) {
    int node = (blockIdx.x * 256 + threadIdx.x) >> 6;
    int lane = threadIdx.x & 63;
    if (node >= N) return;
    int e = row_ptr[node], end = row_end[node];
    float ax = 0.f, ay = 0.f;
    for (; e + 4 <= end; e += 4) {
        int s0 = csr_src[e], s1 = csr_src[e + 1], s2 = csr_src[e + 2], s3 = csr_src[e + 3];
        unsigned u0 = h1b2[(long)s0 * 64 + lane];
        unsigned u1 = h1b2[(long)s1 * 64 + lane];
        unsigned u2 = h1b2[(long)s2 * 64 + lane];
        unsigned u3 = h1b2[(long)s3 * 64 + lane];
        ax += __builtin_bit_cast(float, u0 << 16) + __builtin_bit_cast(float, u1 << 16)
            + __builtin_bit_cast(float, u2 << 16) + __builtin_bit_cast(float, u3 << 16);
        ay += __builtin_bit_cast(float, u0 & 0xffff0000u) + __builtin_bit_cast(float, u1 & 0xffff0000u)
            + __builtin_bit_cast(float, u2 & 0xffff0000u) + __builtin_bit_cast(float, u3 & 0xffff0000u);
    }
    for (; e < end; ++e) {
        unsigned u = h1b2[(long)csr_src[e] * 64 + lane];
        ax += __builtin_bit_cast(float, u << 16);
        ay += __builtin_bit_cast(float, u & 0xffff0000u);
    }
    float2 o; o.x = ax; o.y = ay;
    *(float2*)&agg[(long)node * HID + 2 * lane] = o;
}

// ---------------- GEMM2: h2b = bf16((relu(agg*rs_in+b1)*rs_out) @ W2) [N,128]@[128,40] --
__global__ __launch_bounds__(256) void gemm2_kernel(
    const float* __restrict__ agg1, const float* __restrict__ W2,
    const float* __restrict__ b1, const float* __restrict__ rs_in,
    const float* __restrict__ rs_out, unsigned short* __restrict__ h2b, int N) {
    __shared__ float xs[64][128];
    __shared__ float ws[128][NCLS];
    const int tx = threadIdx.x;
    const int row0 = blockIdx.x * 64;

    for (int idx = tx; idx < 128 * NCLS; idx += 256)
        ((float*)ws)[idx] = W2[idx];
#pragma unroll
    for (int j = 0; j < 32; ++j) {
        int idx = tx + 256 * j;
        int r = idx >> 7, k = idx & 127;
        int gr = row0 + r;
        float v = 0.f;
        if (gr < N)
            v = fmaxf(fmaf(agg1[(long)gr * HID + k], rs_in[gr], b1[k]), 0.f) * rs_out[gr];
        xs[r][k] = v;
    }
    __syncthreads();

    const int wv = tx >> 6, lane = tx & 63;
    if (lane < NCLS) {
        for (int rb = 0; rb < 16; rb += 4) {
            int r = wv * 16 + rb;
            float a0 = 0.f, a1 = 0.f, a2 = 0.f, a3 = 0.f;
            for (int k = 0; k < 128; k += 4) {
                float w0 = ws[k][lane], w1 = ws[k + 1][lane];
                float w2 = ws[k + 2][lane], w3 = ws[k + 3][lane];
                float4 x0 = *(const float4*)&xs[r    ][k];
                float4 x1 = *(const float4*)&xs[r + 1][k];
                float4 x2 = *(const float4*)&xs[r + 2][k];
                float4 x3 = *(const float4*)&xs[r + 3][k];
                a0 = fmaf(x0.x, w0, fmaf(x0.y, w1, fmaf(x0.z, w2, fmaf(x0.w, w3, a0))));
                a1 = fmaf(x1.x, w0, fmaf(x1.y, w1, fmaf(x1.z, w2, fmaf(x1.w, w3, a1))));
                a2 = fmaf(x2.x, w0, fmaf(x2.y, w1, fmaf(x2.z, w2, fmaf(x2.w, w3, a2))));
                a3 = fmaf(x3.x, w0, fmaf(x3.y, w1, fmaf(x3.z, w2, fmaf(x3.w, w3, a3))));
            }
            int gr = row0 + r;
            if (gr     < N) h2b[(long)gr * NCLS + lane] = f2bf(a0);
            if (gr + 1 < N) h2b[(long)(gr + 1) * NCLS + lane] = f2bf(a1);
            if (gr + 2 < N) h2b[(long)(gr + 2) * NCLS + lane] = f2bf(a2);
            if (gr + 3 < N) h2b[(long)(gr + 3) * NCLS + lane] = f2bf(a3);
        }
    }
}

// ---------------- agg2 (pull) + epilogue: thread per (node, col-pair) -------------------
__global__ __launch_bounds__(256) void agg2_kernel(
    const int* __restrict__ row_ptr, const int* __restrict__ row_end,
    const int* __restrict__ csr_src, const unsigned* __restrict__ h2b2,  // [N][20] uint
    const float* __restrict__ rs_in, const float* __restrict__ b2,
    float* __restrict__ out, int N) {
    int i = blockIdx.x * 256 + threadIdx.x;
    if (i >= N * 20) return;
    int node = i / 20;
    int cp   = i - node * 20;
    int e = row_ptr[node], end = row_end[node];
    float ax = 0.f, ay = 0.f;
    for (; e + 4 <= end; e += 4) {
        int s0 = csr_src[e], s1 = csr_src[e + 1], s2 = csr_src[e + 2], s3 = csr_src[e + 3];
        unsigned u0 = h2b2[(long)s0 * 20 + cp];
        unsigned u1 = h2b2[(long)s1 * 20 + cp];
        unsigned u2 = h2b2[(long)s2 * 20 + cp];
        unsigned u3 = h2b2[(long)s3 * 20 + cp];
        ax += __builtin_bit_cast(float, u0 << 16) + __builtin_bit_cast(float, u1 << 16)
            + __builtin_bit_cast(float, u2 << 16) + __builtin_bit_cast(float, u3 << 16);
        ay += __builtin_bit_cast(float, u0 & 0xffff0000u) + __builtin_bit_cast(float, u1 & 0xffff0000u)
            + __builtin_bit_cast(float, u2 & 0xffff0000u) + __builtin_bit_cast(float, u3 & 0xffff0000u);
    }
    for (; e < end; ++e) {
        unsigned u = h2b2[(long)csr_src[e] * 20 + cp];
        ax += __builtin_bit_cast(float, u << 16);
        ay += __builtin_bit_cast(float, u & 0xffff0000u);
    }
    float r = rs_in[node];
    float2 o;
    o.x = fmaf(ax, r, b2[2 * cp]);
    o.y = fmaf(ay, r, b2[2 * cp + 1]);
    *(float2*)&out[(long)node * NCLS + 2 * cp] = o;
}

extern "C" void kernel_launch(void* const* d_in, const int* in_sizes, int n_in,
                              void* d_out, int out_size, void* d_ws, size_t ws_size,
                              hipStream_t stream) {
    const float* x  = (const float*)d_in[0];
    const float* W1 = (const float*)d_in[1];
    const float* b1 = (const float*)d_in[2];
    const float* W2 = (const float*)d_in[3];
    const float* b2 = (const float*)d_in[4];
    const int*  src = (const int*)d_in[5];
    const int*  dst = (const int*)d_in[6];
    const int N = in_sizes[0] / IN_F;
    const int E = in_sizes[5];
    const int NB = (N + SCAN_BS - 1) / SCAN_BS;

    float* wsf    = (float*)d_ws;
    float* rs_out = wsf;                          // N f
    float* rs_in  = wsf + N;                      // N f
    int*   cnt_out= (int*)(wsf + 2 * (long)N);    // N i
    int*   cnt_in = cnt_out + N;                  // N i
    int*   row_ptr= cnt_in + N;                   // N i
    int*   cursor = row_ptr + N;                  // N i
    int*   bsum   = cursor + N;                   // 256 i
    int*   csr_src= bsum + 256;                   // E i
    unsigned short* h1b = (unsigned short*)(csr_src + E);      // N*128 bf16
    float* agg1   = (float*)(h1b + (long)N * HID);             // N*128 f
    unsigned short* h2b = (unsigned short*)(agg1 + (long)N * HID);  // N*40 bf16

    {
        int n4 = (2 * N) / 4;
        zero4_kernel<<<(n4 + 255) / 256, 256, 0, stream>>>((float4*)cnt_out, n4);
    }

    degree_kernel<<<(E + 255) / 256, 256, 0, stream>>>(src, dst, cnt_out, cnt_in, E);
    cvt_rsqrt_kernel<<<(N + 255) / 256, 256, 0, stream>>>(cnt_out, cnt_in, rs_out, rs_in, N);

    scan1_kernel<<<NB, SCAN_BS, 0, stream>>>(cnt_in, row_ptr, bsum, N);
    scan2_kernel<<<1, 256, 0, stream>>>(bsum, NB);
    scan3_kernel<<<(N + 255) / 256, 256, 0, stream>>>(row_ptr, cursor, bsum, N);
    fill_kernel<<<(E + 255) / 256, 256, 0, stream>>>(src, dst, cursor, csr_src, E);

    gemm1_kernel<<<(N + 63) / 64, 256, 0, stream>>>(x, W1, rs_out, h1b, N);
    agg1_kernel<<<(N * 64 + 255) / 256, 256, 0, stream>>>(row_ptr, cursor, csr_src,
                                                          (const unsigned*)h1b, agg1, N);
    gemm2_kernel<<<(N + 63) / 64, 256, 0, stream>>>(agg1, W2, b1, rs_in, rs_out, h2b, N);
    agg2_kernel<<<(N * 20 + 255) / 256, 256, 0, stream>>>(row_ptr, cursor, csr_src,
                                                          (const unsigned*)h2b, rs_in, b2,
                                                          (float*)d_out, N);
}